// Round 16
// baseline (23.386 us; speedup 1.0000x reference)
//
#include <hip/hip_runtime.h>

// Ray-AABB nearest intersection. R rays x B boxes. 2 lanes per ray (even: boxes
// 0..15, odd: 16..31), combined via shfl_xor with strict-< (np.argmin first-min).
//
// Bit-exactness (validated absmax 0.0 R4-R15): Markstein div == RN div given
// exact y=RN(1/rd); separate mul/add roundings for p=ro+t*rd; own-axis band
// check elided; best init = BIG; med3 in-band (finite ordered operands).
//
// Perf facts: VALUBusy 73-75% (issue-bound), VGPR=24, bank conflicts fixed (R13),
// pk-f32 gives no 2x on CDNA4 (R14), probe: body 13.5us + fixed ~8us (R10/R11).
// This round attacks the last latency source: the 6 pair-duplicated scalar global
// ray loads. Rays are block-staged through LDS via coalesced float4 loads (one
// merged barrier with the bbox stage); per-thread ds_read_b32 pattern (bank 3r
// mod 32, all distinct + pair broadcast) is conflict-free. Block=512 -> 1024 WGs
// = exactly 4/CU (the residency observed in R11) -> one full-occupancy pass.

constexpr int BMAX = 32;
constexpr int HALF = BMAX / 2;
constexpr int THREADS = 512;
constexpr int RPB = THREADS / 2;      // 256 rays per block

__device__ __forceinline__ float div_markstein(float a, float b, float y) {
    float q0 = __fmul_rn(a, y);
    float e  = __fmaf_rn(-b, q0, a);   // exact residual
    return __fmaf_rn(e, y, q0);        // == __fdiv_rn(a, b)
}

__global__ __launch_bounds__(THREADS) void ray_aabb_kernel(
    const float* __restrict__ rays_o,
    const float* __restrict__ rays_d,
    const float* __restrict__ bbox,
    float* __restrict__ out_idx,
    float* __restrict__ out_dist,
    int R)
{
    const float BIG = 10000000000.0f;
    const float EPS = 1e-4f;

    // slot(b) = (b&15)*2 + (b>>4): pair-partner (even/odd lane) broadcast addrs
    // differ by 48B (disjoint bank quads) instead of 768B (same banks, 2x serial).
    __shared__ float4 s_q[BMAX][3];
    __shared__ float  s_ro[RPB * 3];   // block's rays_o, staged coalesced
    __shared__ float  s_rd[RPB * 3];   // block's rays_d

    int t = threadIdx.x;
    int ray0 = blockIdx.x * RPB;

    // Coalesced float4 staging: 192 vec4 for rays_o, 192 for rays_d (256 rays x 3).
    // ray0*3 floats = 3072*blockIdx bytes -> 16B-aligned.
    {
        const int NV = RPB * 3 / 4;    // 192
        if (t < NV) {
            reinterpret_cast<float4*>(s_ro)[t] =
                reinterpret_cast<const float4*>(rays_o + (size_t)ray0 * 3)[t];
        } else if (t < 2 * NV) {
            reinterpret_cast<float4*>(s_rd)[t - NV] =
                reinterpret_cast<const float4*>(rays_d + (size_t)ray0 * 3)[t - NV];
        }
    }
    if (t < BMAX) {
        int b = t;
        int slot = (b & 15) * 2 + (b >> 4);
        float lo[3], hi[3], loE[3], hiE[3];
        #pragma unroll
        for (int a = 0; a < 3; ++a) {
            float c = bbox[b * 6 + a];
            float s = bbox[b * 6 + 3 + a];
            float h  = __fmul_rn(s, 0.5f);
            lo[a]  = __fsub_rn(c, h);
            hi[a]  = __fadd_rn(c, h);
            loE[a] = __fsub_rn(lo[a], EPS);
            hiE[a] = __fadd_rn(hi[a], EPS);
        }
        s_q[slot][0] = make_float4(lo[0], hi[0], lo[1], hi[1]);
        s_q[slot][1] = make_float4(lo[2], hi[2], loE[0], loE[1]);
        s_q[slot][2] = make_float4(loE[2], hiE[0], hiE[1], hiE[2]);
    }
    __syncthreads();

    // 2 threads per ray: parity selects box half.
    int lray = t >> 1;                 // ray within block
    int ray  = ray0 + lray;
    int par  = t & 1;                  // 0: boxes [0,16)  1: boxes [16,32)
    if (ray >= R) return;
    int b0   = par * HALF;

    float ro[3], rd[3], y[3];
    #pragma unroll
    for (int a = 0; a < 3; ++a) {
        ro[a] = s_ro[lray * 3 + a];    // bank 3*lray mod 32: distinct per ray, pair broadcast
        float d = s_rd[lray * 3 + a];
        rd[a] = (d == 0.0f) ? 1e-8f : d;
        y[a]  = __fdiv_rn(1.0f, rd[a]);   // exact RN reciprocal (Markstein precondition)
    }

    bool  keep  = false;
    float best  = BIG;   // all-invalid half => (BIG, b0); matches np argmin-of-all-BIG
    int   bestb = b0;

    #pragma unroll 8
    for (int bi = 0; bi < HALF; ++bi) {
        int slot = bi * 2 + par;
        int b    = b0 + bi;            // true box index
        float4 q0 = s_q[slot][0];
        float4 q1 = s_q[slot][1];
        float4 q2 = s_q[slot][2];
        float lo[3]  = {q0.x, q0.z, q1.x};
        float hi[3]  = {q0.y, q0.w, q1.y};
        float loE[3] = {q1.z, q1.w, q2.x};
        float hiE[3] = {q2.y, q2.z, q2.w};

        float entry[3], exitv[3];
        #pragma unroll
        for (int a = 0; a < 3; ++a) {
            float t1 = div_markstein(__fsub_rn(lo[a], ro[a]), rd[a], y[a]);
            float t2 = div_markstein(__fsub_rn(hi[a], ro[a]), rd[a], y[a]);
            entry[a] = fminf(t1, t2);
            exitv[a] = fmaxf(t1, t2);
        }
        // fmax/fmin trees fuse to v_max3_f32 / v_min3_f32.
        float tmm = fmaxf(entry[0], fmaxf(entry[1], entry[2]));
        float tmx = fminf(exitv[0], fminf(exitv[1], exitv[2]));
        keep = keep || ((tmm < tmx) && (tmx > 0.0f));

        // In-band via v_med3_f32 on the two OTHER axes per candidate.
        bool inb[3][3];
        #pragma unroll
        for (int a = 0; a < 3; ++a) {
            int o1 = (a == 0) ? 1 : 0;
            int o2 = (a == 2) ? 1 : 2;
            float m1 = __fmul_rn(entry[o1], rd[a]);   // mul rounded
            float m2 = __fmul_rn(entry[o2], rd[a]);
            float p1 = __fadd_rn(ro[a], m1);          // add rounded (no contraction)
            float p2 = __fadd_rn(ro[a], m2);
            inb[a][o1] = (__builtin_amdgcn_fmed3f(p1, loE[a], hiE[a]) == p1);
            inb[a][o2] = (__builtin_amdgcn_fmed3f(p2, loE[a], hiE[a]) == p2);
        }
        // Select-to-BIG then min tree -> v_min3_f32 fusable.
        float tsel[3];
        #pragma unroll
        for (int cnd = 0; cnd < 3; ++cnd) {
            int a1 = (cnd == 0) ? 1 : 0;
            int a2 = (cnd == 2) ? 1 : 2;
            bool v = (entry[cnd] >= 0.0f) && inb[a1][cnd] && inb[a2][cnd];
            tsel[cnd] = v ? entry[cnd] : BIG;
        }
        float tn = fminf(tsel[0], fminf(tsel[1], tsel[2]));
        if (tn < best) { best = tn; bestb = b; }  // strict <: first-min within half
    }

    // Pair combine: odd lane's half (boxes 16..31) wins only on STRICT < .
    float o_best  = __shfl_xor(best, 1, 64);
    int   o_bestb = __shfl_xor(bestb, 1, 64);
    int   o_keep  = __shfl_xor((int)keep, 1, 64);

    if (par == 0) {
        bool k = keep || (o_keep != 0);
        float fb = best; int fi = bestb;
        if (o_best < fb) { fb = o_best; fi = o_bestb; }   // hi half only if strictly smaller
        out_idx[ray]  = k ? (float)fi : -1.0f;
        out_dist[ray] = k ? fb : -1.0f;
    }
}

extern "C" void kernel_launch(void* const* d_in, const int* in_sizes, int n_in,
                              void* d_out, int out_size, void* d_ws, size_t ws_size,
                              hipStream_t stream) {
    const float* rays_o = (const float*)d_in[0];
    const float* rays_d = (const float*)d_in[1];
    const float* bbox   = (const float*)d_in[2];
    int R = in_sizes[0] / 3;

    float* out = (float*)d_out;
    float* out_idx  = out;
    float* out_dist = out + R;

    const long long total = 2LL * R;                   // 2 threads per ray
    const int blocks = (int)((total + THREADS - 1) / THREADS);  // 1024 = 4 WGs/CU
    ray_aabb_kernel<<<blocks, THREADS, 0, stream>>>(rays_o, rays_d, bbox,
                                                    out_idx, out_dist, R);
}

// Round 17
// 20.863 us; speedup vs baseline: 1.1209x; 1.1209x over previous
//
#include <hip/hip_runtime.h>

// Ray-AABB nearest intersection. R rays x B boxes. 2 lanes per ray (even: boxes
// 0..15, odd: 16..31), combined via shfl_xor with strict-< (np.argmin first-min).
// == R15 (session best, 20.6us) — R16's ray-LDS-staging regressed (+2.8us) and
// is reverted.
//
// Bit-exactness (validated absmax 0.0 R4-R16): Markstein div == RN div given
// exact y=RN(1/rd); separate mul/add roundings for p=ro+t*rd; own-axis band
// check elided; best init = BIG; med3 in-band (finite ordered operands).
//
// Perf facts: VALUBusy 73-75% (issue-bound), VGPR=24, bank conflicts fixed via
// pair-interleaved slots, pk-f32 gives no 2x on CDNA4, probe: body ~13us +
// fixed ~8us (launch/ramp/drain). Block=256 (2048 WGs, 8/CU) is the best shape.

constexpr int BMAX = 32;
constexpr int HALF = BMAX / 2;

__device__ __forceinline__ float div_markstein(float a, float b, float y) {
    float q0 = __fmul_rn(a, y);
    float e  = __fmaf_rn(-b, q0, a);   // exact residual
    return __fmaf_rn(e, y, q0);        // == __fdiv_rn(a, b)
}

__global__ __launch_bounds__(256) void ray_aabb_kernel(
    const float* __restrict__ rays_o,
    const float* __restrict__ rays_d,
    const float* __restrict__ bbox,
    float* __restrict__ out_idx,
    float* __restrict__ out_dist,
    int R)
{
    const float BIG = 10000000000.0f;
    const float EPS = 1e-4f;

    // slot(b) = (b&15)*2 + (b>>4): pair-partner (even/odd lane) broadcast addrs
    // differ by 48B (disjoint bank quads) instead of 768B (same banks, 2x serial).
    // Per slot: q0=(lo0,hi0,lo1,hi1)  q1=(lo2,hi2,loE0,loE1)  q2=(loE2,hiE0,hiE1,hiE2)
    __shared__ float4 s_q[BMAX][3];

    int t = threadIdx.x;
    if (t < BMAX) {
        int b = t;
        int slot = (b & 15) * 2 + (b >> 4);
        float lo[3], hi[3], loE[3], hiE[3];
        #pragma unroll
        for (int a = 0; a < 3; ++a) {
            float c = bbox[b * 6 + a];
            float s = bbox[b * 6 + 3 + a];
            float h  = __fmul_rn(s, 0.5f);
            lo[a]  = __fsub_rn(c, h);
            hi[a]  = __fadd_rn(c, h);
            loE[a] = __fsub_rn(lo[a], EPS);
            hiE[a] = __fadd_rn(hi[a], EPS);
        }
        s_q[slot][0] = make_float4(lo[0], hi[0], lo[1], hi[1]);
        s_q[slot][1] = make_float4(lo[2], hi[2], loE[0], loE[1]);
        s_q[slot][2] = make_float4(loE[2], hiE[0], hiE[1], hiE[2]);
    }
    __syncthreads();

    // 2 threads per ray: parity selects box half.
    int gid  = blockIdx.x * blockDim.x + threadIdx.x;
    int ray  = gid >> 1;
    int par  = gid & 1;          // 0: boxes [0,16)  1: boxes [16,32)
    if (ray >= R) return;
    int b0   = par * HALF;

    float ro[3], rd[3], y[3];
    #pragma unroll
    for (int a = 0; a < 3; ++a) {
        ro[a] = rays_o[ray * 3 + a];
        float d = rays_d[ray * 3 + a];
        rd[a] = (d == 0.0f) ? 1e-8f : d;
        y[a]  = __fdiv_rn(1.0f, rd[a]);   // exact RN reciprocal (Markstein precondition)
    }

    bool  keep  = false;
    float best  = BIG;   // all-invalid half => (BIG, b0); matches np argmin-of-all-BIG
    int   bestb = b0;

    #pragma unroll 8
    for (int bi = 0; bi < HALF; ++bi) {
        int slot = bi * 2 + par;
        int b    = b0 + bi;            // true box index
        float4 q0 = s_q[slot][0];
        float4 q1 = s_q[slot][1];
        float4 q2 = s_q[slot][2];
        float lo[3]  = {q0.x, q0.z, q1.x};
        float hi[3]  = {q0.y, q0.w, q1.y};
        float loE[3] = {q1.z, q1.w, q2.x};
        float hiE[3] = {q2.y, q2.z, q2.w};

        float entry[3], exitv[3];
        #pragma unroll
        for (int a = 0; a < 3; ++a) {
            float t1 = div_markstein(__fsub_rn(lo[a], ro[a]), rd[a], y[a]);
            float t2 = div_markstein(__fsub_rn(hi[a], ro[a]), rd[a], y[a]);
            entry[a] = fminf(t1, t2);
            exitv[a] = fmaxf(t1, t2);
        }
        // fmax/fmin trees fuse to v_max3_f32 / v_min3_f32.
        float tmm = fmaxf(entry[0], fmaxf(entry[1], entry[2]));
        float tmx = fminf(exitv[0], fminf(exitv[1], exitv[2]));
        keep = keep || ((tmm < tmx) && (tmx > 0.0f));

        // In-band via v_med3_f32 on the two OTHER axes per candidate.
        bool inb[3][3];
        #pragma unroll
        for (int a = 0; a < 3; ++a) {
            int o1 = (a == 0) ? 1 : 0;
            int o2 = (a == 2) ? 1 : 2;
            float m1 = __fmul_rn(entry[o1], rd[a]);   // mul rounded
            float m2 = __fmul_rn(entry[o2], rd[a]);
            float p1 = __fadd_rn(ro[a], m1);          // add rounded (no contraction)
            float p2 = __fadd_rn(ro[a], m2);
            inb[a][o1] = (__builtin_amdgcn_fmed3f(p1, loE[a], hiE[a]) == p1);
            inb[a][o2] = (__builtin_amdgcn_fmed3f(p2, loE[a], hiE[a]) == p2);
        }
        // Select-to-BIG then a min tree -> v_min3_f32 fusable.
        float tsel[3];
        #pragma unroll
        for (int cnd = 0; cnd < 3; ++cnd) {
            int a1 = (cnd == 0) ? 1 : 0;
            int a2 = (cnd == 2) ? 1 : 2;
            bool v = (entry[cnd] >= 0.0f) && inb[a1][cnd] && inb[a2][cnd];
            tsel[cnd] = v ? entry[cnd] : BIG;
        }
        float tn = fminf(tsel[0], fminf(tsel[1], tsel[2]));
        if (tn < best) { best = tn; bestb = b; }  // strict <: first-min within half
    }

    // Pair combine: odd lane's half (boxes 16..31) wins only on STRICT < .
    float o_best  = __shfl_xor(best, 1, 64);
    int   o_bestb = __shfl_xor(bestb, 1, 64);
    int   o_keep  = __shfl_xor((int)keep, 1, 64);

    if (par == 0) {
        bool k = keep || (o_keep != 0);
        float fb = best; int fi = bestb;
        if (o_best < fb) { fb = o_best; fi = o_bestb; }   // hi half only if strictly smaller
        out_idx[ray]  = k ? (float)fi : -1.0f;
        out_dist[ray] = k ? fb : -1.0f;
    }
}

extern "C" void kernel_launch(void* const* d_in, const int* in_sizes, int n_in,
                              void* d_out, int out_size, void* d_ws, size_t ws_size,
                              hipStream_t stream) {
    const float* rays_o = (const float*)d_in[0];
    const float* rays_d = (const float*)d_in[1];
    const float* bbox   = (const float*)d_in[2];
    int R = in_sizes[0] / 3;

    float* out = (float*)d_out;
    float* out_idx  = out;
    float* out_dist = out + R;

    const int threads = 256;
    const long long total = 2LL * R;                 // 2 threads per ray
    const int blocks = (int)((total + threads - 1) / threads);
    ray_aabb_kernel<<<blocks, threads, 0, stream>>>(rays_o, rays_d, bbox,
                                                    out_idx, out_dist, R);
}